// Round 2
// baseline (1650.304 us; speedup 1.0000x reference)
//
#include <hip/hip_runtime.h>
#include <hip/hip_fp16.h>

#define FIN 128
#define HID 32
#define BSHIFT 8                 // 256 nodes per coarse bucket
#define BNODES 256
#define CHUNK 2048               // edges per chunk-sort block
#define NBMAX 512                // max coarse buckets supported in LDS
#define CAPB 8960                // max entries per bucket (mean 8184, +8.6 sigma)
#define G1ROWS 64                // rows per gemm block

// ---------------- A: per-chunk counting sort by bucket + global degree count ----------------

__global__ __launch_bounds__(256) void chunk_sort_kernel(const int* __restrict__ src,
                                                         const int* __restrict__ dst,
                                                         int* __restrict__ ec,
                                                         unsigned short* __restrict__ offt,
                                                         int* __restrict__ deg,
                                                         int E, int nb) {
    __shared__ int hist[NBMAX];
    __shared__ int pref[NBMAX];
    __shared__ int sorted[CHUNK];
    int c = blockIdx.x, t = threadIdx.x;
    int beg = c * CHUNK;
    int cnt = min(CHUNK, E - beg);
    for (int i = t; i < nb; i += 256) hist[i] = 0;
    __syncthreads();
    int bk[8], ent[8];
    #pragma unroll
    for (int j = 0; j < 8; ++j) {
        int i = t + j * 256;
        if (i < cnt) {
            int d = dst[beg + i];
            bk[j]  = ((unsigned)d) >> BSHIFT;
            ent[j] = src[beg + i] | ((d & (BNODES - 1)) << 24);
            atomicAdd(&hist[bk[j]], 1);
            atomicAdd(&deg[d], 1);               // global degree (L2-resident 400 KB)
        } else bk[j] = -1;
    }
    __syncthreads();
    // single-wave exclusive scan over nb (<= NBMAX = 64 lanes * 8) buckets
    if (t < 64) {
        int v[8];
        int s = 0;
        #pragma unroll
        for (int j = 0; j < 8; ++j) {
            int idx = t * 8 + j;
            int h = (idx < nb) ? hist[idx] : 0;
            v[j] = s; s += h;
        }
        int run = s;
        #pragma unroll
        for (int d = 1; d < 64; d <<= 1) {
            int o = __shfl_up(run, d, 64);
            if (t >= d) run += o;
        }
        int excl = run - s;
        #pragma unroll
        for (int j = 0; j < 8; ++j) {
            int idx = t * 8 + j;
            if (idx < nb) { int p = excl + v[j]; pref[idx] = p; hist[idx] = p; }
        }
    }
    __syncthreads();
    #pragma unroll
    for (int j = 0; j < 8; ++j) {
        if (bk[j] >= 0) {
            int p = atomicAdd(&hist[bk[j]], 1);
            sorted[p] = ent[j];
        }
    }
    __syncthreads();
    for (int i = t; i < cnt; i += 256) ec[(size_t)c * CHUNK + i] = sorted[i];   // coalesced
    unsigned short* row = offt + (size_t)c * (nb + 1);
    for (int i = t; i < nb; i += 256) row[i] = (unsigned short)pref[i];
    if (t == 0) row[nb] = (unsigned short)cnt;
}

// ---------------- GEMM1: h16 = (x @ W1) * dinv; dinv computed inline from deg ----------------

__global__ __launch_bounds__(256) void gemm1_kernel(const float* __restrict__ x,
                                                    const float* __restrict__ W,
                                                    const int* __restrict__ deg,
                                                    __half* __restrict__ h16, int n) {
    __shared__ float Ws[FIN * HID];              // 16 KB
    int t = threadIdx.x;
    for (int i = t; i < FIN * HID; i += 256) Ws[i] = W[i];
    __syncthreads();
    int row0 = blockIdx.x * G1ROWS;
    int tr = t >> 3, tc = t & 7;
    int r0 = row0 + tr * 2, c0 = tc * 4;
    bool v0 = r0 < n, v1 = (r0 + 1) < n;
    const float* p0 = v0 ? &x[(size_t)r0 * FIN] : x;        // safe dummy row
    const float* p1 = v1 ? &x[(size_t)(r0 + 1) * FIN] : x;
    float4 a0 = make_float4(0.f, 0.f, 0.f, 0.f);
    float4 a1 = make_float4(0.f, 0.f, 0.f, 0.f);
    #pragma unroll 8
    for (int k4 = 0; k4 < FIN / 4; ++k4) {
        float4 xv0 = *(const float4*)&p0[k4 * 4];
        float4 xv1 = *(const float4*)&p1[k4 * 4];
        float4 w0 = *(const float4*)&Ws[(k4 * 4 + 0) * HID + c0];
        float4 w1 = *(const float4*)&Ws[(k4 * 4 + 1) * HID + c0];
        float4 w2 = *(const float4*)&Ws[(k4 * 4 + 2) * HID + c0];
        float4 w3 = *(const float4*)&Ws[(k4 * 4 + 3) * HID + c0];
        a0.x = fmaf(xv0.x, w0.x, a0.x); a0.y = fmaf(xv0.x, w0.y, a0.y);
        a0.z = fmaf(xv0.x, w0.z, a0.z); a0.w = fmaf(xv0.x, w0.w, a0.w);
        a0.x = fmaf(xv0.y, w1.x, a0.x); a0.y = fmaf(xv0.y, w1.y, a0.y);
        a0.z = fmaf(xv0.y, w1.z, a0.z); a0.w = fmaf(xv0.y, w1.w, a0.w);
        a0.x = fmaf(xv0.z, w2.x, a0.x); a0.y = fmaf(xv0.z, w2.y, a0.y);
        a0.z = fmaf(xv0.z, w2.z, a0.z); a0.w = fmaf(xv0.z, w2.w, a0.w);
        a0.x = fmaf(xv0.w, w3.x, a0.x); a0.y = fmaf(xv0.w, w3.y, a0.y);
        a0.z = fmaf(xv0.w, w3.z, a0.z); a0.w = fmaf(xv0.w, w3.w, a0.w);
        a1.x = fmaf(xv1.x, w0.x, a1.x); a1.y = fmaf(xv1.x, w0.y, a1.y);
        a1.z = fmaf(xv1.x, w0.z, a1.z); a1.w = fmaf(xv1.x, w0.w, a1.w);
        a1.x = fmaf(xv1.y, w1.x, a1.x); a1.y = fmaf(xv1.y, w1.y, a1.y);
        a1.z = fmaf(xv1.y, w1.z, a1.z); a1.w = fmaf(xv1.y, w1.w, a1.w);
        a1.x = fmaf(xv1.z, w2.x, a1.x); a1.y = fmaf(xv1.z, w2.y, a1.y);
        a1.z = fmaf(xv1.z, w2.z, a1.z); a1.w = fmaf(xv1.z, w2.w, a1.w);
        a1.x = fmaf(xv1.w, w3.x, a1.x); a1.y = fmaf(xv1.w, w3.y, a1.y);
        a1.z = fmaf(xv1.w, w3.z, a1.z); a1.w = fmaf(xv1.w, w3.w, a1.w);
    }
    #pragma unroll
    for (int rr = 0; rr < 2; ++rr) {
        int row = r0 + rr;
        float4 a = rr ? a1 : a0;
        float sc = (row < n) ? rsqrtf((float)deg[row] + 1.0f) : 0.f;
        __half2 q0 = __floats2half2_rn(a.x * sc, a.y * sc);
        __half2 q1 = __floats2half2_rn(a.z * sc, a.w * sc);
        __half2* dstp = (__half2*)&h16[(size_t)row * HID + c0];
        dstp[0] = q0;
        dstp[1] = q1;
    }
}

// ---------------- fused scatter: gather runs -> LDS edge list -> ds_add_f32 accumulate
// epilogue: relu(b + di*(acc+self)); LAST=0 additionally applies W2 GEMM + dinv -> h16 out ----

template <int LAST>
__global__ __launch_bounds__(1024) void scatter_kernel(const int* __restrict__ ec,
                                                       const unsigned short* __restrict__ offt,
                                                       const int* __restrict__ deg,
                                                       const __half* __restrict__ h16,
                                                       const float* __restrict__ bias,
                                                       const float* __restrict__ W2,
                                                       __half* __restrict__ outh,
                                                       float* __restrict__ outf,
                                                       int n, int nb, int nchunks) {
    __shared__ int raw[CAPB];                    // 35.8 KB
    __shared__ float acc[BNODES][HID + 1];       // 33.8 KB, stride 33 -> bank (r+k)%32
    __shared__ float Ws[HID * HID];              // 4 KB (layer-1 only)
    __shared__ int nfill;
    int b = blockIdx.x, t = threadIdx.x;
    for (int i = t; i < BNODES * (HID + 1); i += 1024) (&acc[0][0])[i] = 0.f;
    if (!LAST) for (int i = t; i < HID * HID; i += 1024) Ws[i] = W2[i];
    if (t == 0) nfill = 0;
    __syncthreads();
    // ---- phase 1: gather this bucket's runs from every chunk into LDS ----
    for (int c = t; c < nchunks; c += 1024) {
        const unsigned short* row = offt + (size_t)c * (nb + 1);
        int s = row[b], e2 = row[b + 1];
        int m = e2 - s;
        if (m > 0) {
            int base = atomicAdd(&nfill, m);
            const int* p = ec + (size_t)c * CHUNK + s;
            int k = 0;
            for (; k + 4 <= m; k += 4) {           // 4 independent loads in flight
                int e0 = p[k], e1 = p[k + 1], e2v = p[k + 2], e3 = p[k + 3];
                if (base + k + 0 < CAPB) raw[base + k + 0] = e0;
                if (base + k + 1 < CAPB) raw[base + k + 1] = e1;
                if (base + k + 2 < CAPB) raw[base + k + 2] = e2v;
                if (base + k + 3 < CAPB) raw[base + k + 3] = e3;
            }
            for (; k < m; ++k) {
                int e = p[k];
                if (base + k < CAPB) raw[base + k] = e;
            }
        }
    }
    __syncthreads();
    int total = min(nfill, CAPB);
    // ---- phase 2: edge-parallel accumulate into acc via LDS float atomics ----
    for (int i = t; i < total; i += 1024) {
        int e = raw[i];
        int sv = e & 0xFFFFFF;
        int dl = ((unsigned)e) >> 24;
        const float4* hp = (const float4*)(h16 + (size_t)sv * HID);
        float4 v0 = hp[0], v1 = hp[1], v2 = hp[2], v3 = hp[3];   // 64 B row, 4 loads in flight
        float* ar = acc[dl];
        float4 vv[4] = {v0, v1, v2, v3};
        #pragma unroll
        for (int h = 0; h < 4; ++h) {
            const __half2* q = (const __half2*)&vv[h];
            #pragma unroll
            for (int j = 0; j < 4; ++j) {
                float2 f = __half22float2(q[j]);
                atomicAdd(&ar[h * 8 + j * 2 + 0], f.x);
                atomicAdd(&ar[h * 8 + j * 2 + 1], f.y);
            }
        }
    }
    __syncthreads();
    // ---- epilogue: 4 threads per node, 8 feats each ----
    int r  = t >> 2;
    int c0 = (t & 3) * 8;
    int node = b * BNODES + r;
    bool valid = (node < n);
    float di = 0.f;
    float rl[8];
    if (valid) {
        di = rsqrtf((float)deg[node] + 1.0f);
        float4 sv = *(const float4*)(h16 + (size_t)node * HID + c0);  // self term (8 halves)
        const __half2* sh = (const __half2*)&sv;
        float4 bb0 = *(const float4*)(bias + c0);
        float4 bb1 = *(const float4*)(bias + c0 + 4);
        float bj[8] = {bb0.x, bb0.y, bb0.z, bb0.w, bb1.x, bb1.y, bb1.z, bb1.w};
        #pragma unroll
        for (int j = 0; j < 4; ++j) {
            float2 f = __half22float2(sh[j]);
            rl[2 * j]     = fmaxf(bj[2 * j]     + di * (acc[r][c0 + 2 * j]     + f.x), 0.f);
            rl[2 * j + 1] = fmaxf(bj[2 * j + 1] + di * (acc[r][c0 + 2 * j + 1] + f.y), 0.f);
        }
    }
    if (LAST) {
        if (valid) {
            float* op = outf + (size_t)node * HID + c0;
            *(float4*)op       = make_float4(rl[0], rl[1], rl[2], rl[3]);
            *(float4*)(op + 4) = make_float4(rl[4], rl[5], rl[6], rl[7]);
        }
    } else {
        if (valid) {
            #pragma unroll
            for (int j = 0; j < 8; ++j) acc[r][c0 + j] = rl[j];   // relu'd row back to LDS
        }
        __syncthreads();                                          // uniform (template branch)
        if (valid) {
            float o[8] = {0.f, 0.f, 0.f, 0.f, 0.f, 0.f, 0.f, 0.f};
            #pragma unroll 8
            for (int k = 0; k < HID; ++k) {
                float a = acc[r][k];
                float4 w0 = *(const float4*)&Ws[k * HID + c0];
                float4 w1 = *(const float4*)&Ws[k * HID + c0 + 4];
                o[0] = fmaf(a, w0.x, o[0]); o[1] = fmaf(a, w0.y, o[1]);
                o[2] = fmaf(a, w0.z, o[2]); o[3] = fmaf(a, w0.w, o[3]);
                o[4] = fmaf(a, w1.x, o[4]); o[5] = fmaf(a, w1.y, o[5]);
                o[6] = fmaf(a, w1.z, o[6]); o[7] = fmaf(a, w1.w, o[7]);
            }
            float4 tmp;
            __half2* hp2 = (__half2*)&tmp;
            #pragma unroll
            for (int j = 0; j < 4; ++j) hp2[j] = __floats2half2_rn(di * o[2 * j], di * o[2 * j + 1]);
            *(float4*)(outh + (size_t)node * HID + c0) = tmp;     // h16 for layer 2
        }
    }
}

extern "C" void kernel_launch(void* const* d_in, const int* in_sizes, int n_in,
                              void* d_out, int out_size, void* d_ws, size_t ws_size,
                              hipStream_t stream) {
    const float* x  = (const float*)d_in[0];
    const int*   ei = (const int*)d_in[1];
    const float* W1 = (const float*)d_in[2];
    const float* b1 = (const float*)d_in[3];
    const float* W2 = (const float*)d_in[4];
    const float* b2 = (const float*)d_in[5];
    float* out = (float*)d_out;

    int n = in_sizes[0] / FIN;      // 100000
    int E = in_sizes[1] / 2;        // 3200000
    const int* src = ei;
    const int* dst = ei + E;

    int nb = (n + BNODES - 1) / BNODES;          // 391 buckets
    int nchunks = (E + CHUNK - 1) / CHUNK;       // 1563 chunks
    int ggrid = (n + G1ROWS) / G1ROWS;
    int npad = ggrid * G1ROWS;

    char* ws = (char*)d_ws;
    size_t off = 0;
    auto alloc = [&](size_t bytes) { char* p = ws + off; off += (bytes + 255) & ~(size_t)255; return p; };
    int*            ec   = (int*)alloc((size_t)nchunks * CHUNK * 4);              // 12.8 MB
    unsigned short* offt = (unsigned short*)alloc((size_t)nchunks * (nb + 1) * 2); // 1.2 MB
    int*            deg  = (int*)alloc((size_t)n * 4);                            // 0.4 MB
    __half*         hha  = (__half*)alloc((size_t)npad * HID * 2);                // 6.4 MB
    __half*         hhb  = (__half*)alloc((size_t)n * HID * 2);                   // 6.4 MB

    hipMemsetAsync(deg, 0, (size_t)n * 4, stream);

    // ---- preprocessing: chunk sort (+degree) ----
    chunk_sort_kernel<<<nchunks, 256, 0, stream>>>(src, dst, ec, offt, deg, E, nb);

    // ---- layer 1 GEMM ----
    gemm1_kernel<<<ggrid, 256, 0, stream>>>(x, W1, deg, hha, n);

    // ---- layer 1 scatter + fused layer 2 GEMM ----
    scatter_kernel<0><<<nb, 1024, 0, stream>>>(ec, offt, deg, hha, b1, W2, hhb, nullptr, n, nb, nchunks);

    // ---- layer 2 scatter -> final output ----
    scatter_kernel<1><<<nb, 1024, 0, stream>>>(ec, offt, deg, hhb, b2, nullptr, nullptr, out, n, nb, nchunks);
}

// Round 3
// 242.633 us; speedup vs baseline: 6.8016x; 6.8016x over previous
//
#include <hip/hip_runtime.h>
#include <hip/hip_fp16.h>

#define FIN 128
#define HID 32
#define BSHIFT 8                 // 256 nodes per coarse bucket
#define BNODES 256
#define CHUNK 2048               // edges per chunk-sort block
#define NBMAX 512                // max coarse buckets supported in LDS
#define CAPB 8960                // max entries per bucket (mean 8184, +8.6 sigma)
#define G1ROWS 64                // rows per gemm block
#define XPAD 4                   // LDS leading-dim pad

// ---------------- A: per-chunk counting sort by bucket (all I/O coalesced) ----------------

__global__ __launch_bounds__(256) void chunk_sort_kernel(const int* __restrict__ src,
                                                         const int* __restrict__ dst,
                                                         int* __restrict__ ec,
                                                         unsigned short* __restrict__ offt,
                                                         int E, int nb) {
    __shared__ int hist[NBMAX];
    __shared__ int pref[NBMAX];
    __shared__ int sorted[CHUNK];
    int c = blockIdx.x, t = threadIdx.x;
    int beg = c * CHUNK;
    int cnt = min(CHUNK, E - beg);
    for (int i = t; i < nb; i += 256) hist[i] = 0;
    __syncthreads();
    int bk[8], ent[8];
    #pragma unroll
    for (int j = 0; j < 8; ++j) {
        int i = t + j * 256;
        if (i < cnt) {
            int d = dst[beg + i];
            bk[j]  = ((unsigned)d) >> BSHIFT;
            ent[j] = src[beg + i] | ((d & (BNODES - 1)) << 24);
            atomicAdd(&hist[bk[j]], 1);
        } else bk[j] = -1;
    }
    __syncthreads();
    // single-wave exclusive scan over nb (<= NBMAX = 64 lanes * 8) buckets
    if (t < 64) {
        int v[8];
        int s = 0;
        #pragma unroll
        for (int j = 0; j < 8; ++j) {
            int idx = t * 8 + j;
            int h = (idx < nb) ? hist[idx] : 0;
            v[j] = s; s += h;
        }
        int run = s;
        #pragma unroll
        for (int d = 1; d < 64; d <<= 1) {
            int o = __shfl_up(run, d, 64);
            if (t >= d) run += o;
        }
        int excl = run - s;
        #pragma unroll
        for (int j = 0; j < 8; ++j) {
            int idx = t * 8 + j;
            if (idx < nb) { int p = excl + v[j]; pref[idx] = p; hist[idx] = p; }
        }
    }
    __syncthreads();
    #pragma unroll
    for (int j = 0; j < 8; ++j) {
        if (bk[j] >= 0) {
            int p = atomicAdd(&hist[bk[j]], 1);
            sorted[p] = ent[j];
        }
    }
    __syncthreads();
    for (int i = t; i < cnt; i += 256) ec[(size_t)c * CHUNK + i] = sorted[i];   // coalesced
    unsigned short* row = offt + (size_t)c * (nb + 1);
    for (int i = t; i < nb; i += 256) row[i] = (unsigned short)pref[i];
    if (t == 0) row[nb] = (unsigned short)cnt;
}

// ---------------- B: per-bucket gather of chunk runs + node counting sort ----------------

__global__ __launch_bounds__(1024) void bucket_build_kernel(const int* __restrict__ ec,
                                                            const unsigned short* __restrict__ offt,
                                                            int* __restrict__ entries,
                                                            float* __restrict__ dinv,
                                                            int* __restrict__ rowbeg,
                                                            int* __restrict__ rowcnt,
                                                            int n, int nb, int nchunks, int cap) {
    __shared__ int raw[CAPB];
    __shared__ int srt[CAPB];
    __shared__ int hist[BNODES];
    __shared__ int pref[BNODES];
    __shared__ int cursor[BNODES];
    __shared__ int nfill;
    int b = blockIdx.x, t = threadIdx.x;
    if (t < BNODES) hist[t] = 0;
    if (t == 0) nfill = 0;
    __syncthreads();
    for (int c = t; c < nchunks; c += 1024) {
        const unsigned short* row = offt + (size_t)c * (nb + 1);
        int s = row[b], e2 = row[b + 1];
        int m = e2 - s;
        if (m > 0) {
            int base = atomicAdd(&nfill, m);
            const int* p = ec + (size_t)c * CHUNK + s;
            int k = 0;
            for (; k + 4 <= m; k += 4) {           // 4 independent loads in flight
                int e0 = p[k], e1 = p[k + 1], e2v = p[k + 2], e3 = p[k + 3];
                if (base + k + 0 < CAPB) raw[base + k + 0] = e0;
                if (base + k + 1 < CAPB) raw[base + k + 1] = e1;
                if (base + k + 2 < CAPB) raw[base + k + 2] = e2v;
                if (base + k + 3 < CAPB) raw[base + k + 3] = e3;
                atomicAdd(&hist[((unsigned)e0) >> 24], 1);
                atomicAdd(&hist[((unsigned)e1) >> 24], 1);
                atomicAdd(&hist[((unsigned)e2v) >> 24], 1);
                atomicAdd(&hist[((unsigned)e3) >> 24], 1);
            }
            for (; k < m; ++k) {
                int e = p[k];
                if (base + k < CAPB) raw[base + k] = e;
                atomicAdd(&hist[((unsigned)e) >> 24], 1);
            }
        }
    }
    __syncthreads();
    int total = min(nfill, CAPB);
    // single-wave exclusive scan over 256 node counts (64 lanes * 4)
    if (t < 64) {
        int v[4];
        int s = 0;
        #pragma unroll
        for (int j = 0; j < 4; ++j) { v[j] = s; s += hist[t * 4 + j]; }
        int run = s;
        #pragma unroll
        for (int d = 1; d < 64; d <<= 1) {
            int o = __shfl_up(run, d, 64);
            if (t >= d) run += o;
        }
        int excl = run - s;
        #pragma unroll
        for (int j = 0; j < 4; ++j) {
            int idx = t * 4 + j;
            int p = excl + v[j];
            pref[idx] = p; cursor[idx] = p;
        }
    }
    __syncthreads();
    for (int i = t; i < total; i += 1024) {
        int e = raw[i];
        int p = atomicAdd(&cursor[((unsigned)e) >> 24], 1);
        srt[p] = e;
    }
    __syncthreads();
    int* ep = entries + (size_t)b * cap;
    for (int i = t; i < total; i += 1024) ep[i] = srt[i];
    int node = b * BNODES + t;
    if (t < BNODES && node < n) {
        int deg = hist[t];
        dinv[node]   = rsqrtf((float)deg + 1.0f);   // +1 = self-loop
        rowbeg[node] = b * cap + pref[t];
        rowcnt[node] = deg;
    }
}

// ---------------- GEMM1: h16 = (x @ W1) * dinv; x read direct from global ----------------

__global__ __launch_bounds__(256) void gemm1_kernel(const float* __restrict__ x,
                                                    const float* __restrict__ W,
                                                    const float* __restrict__ dinv,
                                                    __half* __restrict__ h16, int n) {
    __shared__ float Ws[FIN * HID];              // 16 KB
    int t = threadIdx.x;
    for (int i = t; i < FIN * HID; i += 256) Ws[i] = W[i];
    __syncthreads();
    int row0 = blockIdx.x * G1ROWS;
    int tr = t >> 3, tc = t & 7;
    int r0 = row0 + tr * 2, c0 = tc * 4;
    bool v0 = r0 < n, v1 = (r0 + 1) < n;
    const float* p0 = v0 ? &x[(size_t)r0 * FIN] : x;        // safe dummy row
    const float* p1 = v1 ? &x[(size_t)(r0 + 1) * FIN] : x;
    float4 a0 = make_float4(0.f, 0.f, 0.f, 0.f);
    float4 a1 = make_float4(0.f, 0.f, 0.f, 0.f);
    #pragma unroll 8
    for (int k4 = 0; k4 < FIN / 4; ++k4) {
        float4 xv0 = *(const float4*)&p0[k4 * 4];
        float4 xv1 = *(const float4*)&p1[k4 * 4];
        float4 w0 = *(const float4*)&Ws[(k4 * 4 + 0) * HID + c0];
        float4 w1 = *(const float4*)&Ws[(k4 * 4 + 1) * HID + c0];
        float4 w2 = *(const float4*)&Ws[(k4 * 4 + 2) * HID + c0];
        float4 w3 = *(const float4*)&Ws[(k4 * 4 + 3) * HID + c0];
        a0.x = fmaf(xv0.x, w0.x, a0.x); a0.y = fmaf(xv0.x, w0.y, a0.y);
        a0.z = fmaf(xv0.x, w0.z, a0.z); a0.w = fmaf(xv0.x, w0.w, a0.w);
        a0.x = fmaf(xv0.y, w1.x, a0.x); a0.y = fmaf(xv0.y, w1.y, a0.y);
        a0.z = fmaf(xv0.y, w1.z, a0.z); a0.w = fmaf(xv0.y, w1.w, a0.w);
        a0.x = fmaf(xv0.z, w2.x, a0.x); a0.y = fmaf(xv0.z, w2.y, a0.y);
        a0.z = fmaf(xv0.z, w2.z, a0.z); a0.w = fmaf(xv0.z, w2.w, a0.w);
        a0.x = fmaf(xv0.w, w3.x, a0.x); a0.y = fmaf(xv0.w, w3.y, a0.y);
        a0.z = fmaf(xv0.w, w3.z, a0.z); a0.w = fmaf(xv0.w, w3.w, a0.w);
        a1.x = fmaf(xv1.x, w0.x, a1.x); a1.y = fmaf(xv1.x, w0.y, a1.y);
        a1.z = fmaf(xv1.x, w0.z, a1.z); a1.w = fmaf(xv1.x, w0.w, a1.w);
        a1.x = fmaf(xv1.y, w1.x, a1.x); a1.y = fmaf(xv1.y, w1.y, a1.y);
        a1.z = fmaf(xv1.y, w1.z, a1.z); a1.w = fmaf(xv1.y, w1.w, a1.w);
        a1.x = fmaf(xv1.z, w2.x, a1.x); a1.y = fmaf(xv1.z, w2.y, a1.y);
        a1.z = fmaf(xv1.z, w2.z, a1.z); a1.w = fmaf(xv1.z, w2.w, a1.w);
        a1.x = fmaf(xv1.w, w3.x, a1.x); a1.y = fmaf(xv1.w, w3.y, a1.y);
        a1.z = fmaf(xv1.w, w3.z, a1.z); a1.w = fmaf(xv1.w, w3.w, a1.w);
    }
    #pragma unroll
    for (int rr = 0; rr < 2; ++rr) {
        int row = r0 + rr;
        float4 a = rr ? a1 : a0;
        float sc = (row < n) ? dinv[row] : 0.f;
        __half2 q0 = __floats2half2_rn(a.x * sc, a.y * sc);
        __half2 q1 = __floats2half2_rn(a.z * sc, a.w * sc);
        __half2* dstp = (__half2*)&h16[(size_t)row * HID + c0];
        dstp[0] = q0;
        dstp[1] = q1;
    }
}

// ---------------- gather: 4-lane groups, lane owns 8 feats, float4 (16B) loads ----------------
// FUSEW2=1: after relu, apply W2 (32x32) via width-4 shuffles + LDS weights, write h16 for
// layer 2 (pre-scaled by dinv).  FUSEW2=0: write final fp32 output.

template <int FUSEW2>
__global__ __launch_bounds__(256) void gather_kernel(const int* __restrict__ entries,
                                                     const int* __restrict__ rowbeg,
                                                     const int* __restrict__ rowcnt,
                                                     const float* __restrict__ dinv,
                                                     const __half* __restrict__ h16,
                                                     const float* __restrict__ bias,
                                                     const float* __restrict__ W2,
                                                     __half* __restrict__ houth,
                                                     float* __restrict__ outf,
                                                     int n, int sent) {
    __shared__ float Ws[HID * HID];              // 4 KB, FUSEW2 only
    int t = threadIdx.x;
    if (FUSEW2) {
        for (int i = t; i < HID * HID; i += 256) Ws[i] = W2[i];
        __syncthreads();                          // all threads reach this before any return
    }
    int g = t >> 2, f = t & 3;           // 64 nodes/block; lane owns feats [f*8, f*8+8)
    int i = blockIdx.x * 64 + g;
    if (i >= n) return;
    float di = dinv[i];
    float a[8];
    {   // self term: h16 row already carries dinv[i]
        float4 sv4 = *(const float4*)&h16[(size_t)i * HID + f * 8];
        const __half2* sh = (const __half2*)&sv4;
        #pragma unroll
        for (int q = 0; q < 4; ++q) {
            float2 fp = __half22float2(sh[q]);
            a[2 * q] = fp.x; a[2 * q + 1] = fp.y;
        }
    }
    int beg = rowbeg[i], cnt = rowcnt[i];
    for (int base = 0; base < cnt; base += 8) {
        int i0 = base + f, i1 = base + 4 + f;
        int sv0 = (i0 < cnt) ? entries[beg + i0] : sent;   // sentinel = zero row n
        int sv1 = (i1 < cnt) ? entries[beg + i1] : sent;
        sv0 &= 0xFFFFFF; sv1 &= 0xFFFFFF;
        float4 hv[8];
        #pragma unroll
        for (int j = 0; j < 4; ++j) {
            int e = __shfl(sv0, j, 4);
            hv[j] = *(const float4*)&h16[(size_t)e * HID + f * 8];
        }
        #pragma unroll
        for (int j = 0; j < 4; ++j) {
            int e = __shfl(sv1, j, 4);
            hv[4 + j] = *(const float4*)&h16[(size_t)e * HID + f * 8];
        }
        #pragma unroll
        for (int j = 0; j < 8; ++j) {
            const __half2* hp = (const __half2*)&hv[j];
            #pragma unroll
            for (int q = 0; q < 4; ++q) {
                float2 fp = __half22float2(hp[q]);
                a[2 * q] += fp.x; a[2 * q + 1] += fp.y;
            }
        }
    }
    // relu(b + di * a)  -> rl[8]
    float4 b0 = *(const float4*)&bias[f * 8];
    float4 b1 = *(const float4*)&bias[f * 8 + 4];
    float bj[8] = {b0.x, b0.y, b0.z, b0.w, b1.x, b1.y, b1.z, b1.w};
    float rl[8];
    #pragma unroll
    for (int j = 0; j < 8; ++j) rl[j] = fmaxf(bj[j] + di * a[j], 0.f);

    if (!FUSEW2) {
        *(float4*)&outf[(size_t)i * HID + f * 8]     = make_float4(rl[0], rl[1], rl[2], rl[3]);
        *(float4*)&outf[(size_t)i * HID + f * 8 + 4] = make_float4(rl[4], rl[5], rl[6], rl[7]);
    } else {
        // layer-2 GEMM: o[c] = sum_k rl_full[k] * W2[k][c]; 4-lane group holds full row.
        int c0 = f * 8;
        float o[8] = {0.f, 0.f, 0.f, 0.f, 0.f, 0.f, 0.f, 0.f};
        #pragma unroll
        for (int s = 0; s < 4; ++s) {
            #pragma unroll
            for (int j = 0; j < 8; ++j) {
                float av = __shfl(rl[j], s, 4);      // lane s of group owns k = s*8+j
                int k = s * 8 + j;
                float4 w0 = *(const float4*)&Ws[k * HID + c0];
                float4 w1 = *(const float4*)&Ws[k * HID + c0 + 4];
                o[0] = fmaf(av, w0.x, o[0]); o[1] = fmaf(av, w0.y, o[1]);
                o[2] = fmaf(av, w0.z, o[2]); o[3] = fmaf(av, w0.w, o[3]);
                o[4] = fmaf(av, w1.x, o[4]); o[5] = fmaf(av, w1.y, o[5]);
                o[6] = fmaf(av, w1.z, o[6]); o[7] = fmaf(av, w1.w, o[7]);
            }
        }
        float4 tmp;
        __half2* hp2 = (__half2*)&tmp;
        #pragma unroll
        for (int j = 0; j < 4; ++j) hp2[j] = __floats2half2_rn(di * o[2 * j], di * o[2 * j + 1]);
        *(float4*)&houth[(size_t)i * HID + f * 8] = tmp;     // h16 input for layer 2
    }
}

extern "C" void kernel_launch(void* const* d_in, const int* in_sizes, int n_in,
                              void* d_out, int out_size, void* d_ws, size_t ws_size,
                              hipStream_t stream) {
    const float* x  = (const float*)d_in[0];
    const int*   ei = (const int*)d_in[1];
    const float* W1 = (const float*)d_in[2];
    const float* b1 = (const float*)d_in[3];
    const float* W2 = (const float*)d_in[4];
    const float* b2 = (const float*)d_in[5];
    float* out = (float*)d_out;

    int n = in_sizes[0] / FIN;      // 100000
    int E = in_sizes[1] / 2;        // 3200000
    const int* src = ei;
    const int* dst = ei + E;

    int nb = (n + BNODES - 1) / BNODES;          // 391 buckets
    int nchunks = (E + CHUNK - 1) / CHUNK;       // 1563 chunks
    int ggrid = (n + G1ROWS) / G1ROWS;           // covers sentinel row n
    int npad = ggrid * G1ROWS;
    int cap = CAPB;

    char* ws = (char*)d_ws;
    size_t off = 0;
    auto alloc = [&](size_t bytes) { char* p = ws + off; off += (bytes + 255) & ~(size_t)255; return p; };
    int*            ec      = (int*)alloc((size_t)nchunks * CHUNK * 4);         // 12.8 MB
    unsigned short* offt    = (unsigned short*)alloc((size_t)nchunks * (nb + 1) * 2); // 1.2 MB
    int*            entries = (int*)alloc((size_t)nb * cap * 4);                // 14.0 MB
    float*          dinv    = (float*)alloc((size_t)n * 4);
    int*            rowbeg  = (int*)alloc((size_t)n * 4);
    int*            rowcnt  = (int*)alloc((size_t)n * 4);
    __half*         hha     = (__half*)alloc((size_t)npad * HID * 2);           // 6.4 MB (gemm1 out)
    __half*         hhb     = (__half*)alloc((size_t)(n + 1) * HID * 2);        // 6.4 MB (layer2 in)

    // sentinel row n of hhb must be zero (gather reads it for tail lanes)
    hipMemsetAsync(hhb + (size_t)n * HID, 0, HID * 2, stream);

    // ---- preprocessing: chunk sort (coalesced) -> bucket build (gather) ----
    chunk_sort_kernel<<<nchunks, 256, 0, stream>>>(src, dst, ec, offt, E, nb);
    bucket_build_kernel<<<nb, 1024, 0, stream>>>(ec, offt, entries, dinv, rowbeg, rowcnt,
                                                 n, nb, nchunks, cap);

    // ---- layer 1: GEMM1 -> gather(+relu) -> fused W2 -> hhb ----
    gemm1_kernel<<<ggrid, 256, 0, stream>>>(x, W1, dinv, hha, n);
    gather_kernel<1><<<(n + 63) / 64, 256, 0, stream>>>(entries, rowbeg, rowcnt, dinv, hha,
                                                        b1, W2, hhb, nullptr, n, n);

    // ---- layer 2: gather(+relu) -> final output ----
    gather_kernel<0><<<(n + 63) / 64, 256, 0, stream>>>(entries, rowbeg, rowcnt, dinv, hhb,
                                                        b2, nullptr, nullptr, out, n, n);
}